// Round 5
// baseline (356.657 us; speedup 1.0000x reference)
//
#include <hip/hip_runtime.h>
#include <cstdint>
#include <cstddef>

// COINBlock (RetNet-style retention, parallel form) on MI355X.
// Shapes: B=2, T=4096, I=C=1024.
//   Q = X@Wq, K = X@Wk, V = X@Wv            (bf16 MFMA, fp32 accum)
//   P = (Q K^T) * D,  D[n,m] = g^(n-m)*[n>=m]   (lower-tri tiles only)
//   out^T[i][t] = sum_m V^T[i][m] * P[t][m]     (output IS the transposed layout)
//   S_n passthrough (zeros) -> memset.
// All GEMMs are gemm_bt form: C[m][n] = sum_k A[m][k]*B[n][k], A/B row-major k-contiguous.
// R3: k_pv split-K + fp32 HW atomics into pre-zeroed out.
// R4: double-buffer + XOR swizzle (bank conflicts 4.3M -> 0).
// R5: AITER-style K-loop: buffer_load->VGPR (tile k+2), ds_write (tile k+1, precise
//     vmcnt), barrier (lgkmcnt-only: VGPR loads are thread-private and survive it),
//     ds_read+MFMA (tile k). Prefetch distance = 2 full iterations > HBM latency.
//     global_load_lds removed — it forced vmcnt(0) at every barrier (the R2-R4 stall).

using bf16x8 = __attribute__((ext_vector_type(8))) short;
using s16x4  = __attribute__((ext_vector_type(4))) short;
using f32x4  = __attribute__((ext_vector_type(4))) float;

#define TM 128
#define BK 32
#define TILE_SH 4096   // shorts per 128x32 tile (8 KB)
#define T_SEQ 4096
#define C_DIM 1024

static constexpr float L2G = -0.0144995697f; // log2(0.99)

__device__ __forceinline__ short f2bf(float f) {
  unsigned u = __builtin_bit_cast(unsigned, f);
  u += 0x7FFFu + ((u >> 16) & 1u);   // round-to-nearest-even
  return (short)(u >> 16);
}

// K-loop core: 128x128 tile, 4 waves in 2x2, each wave 4x4 of 16x16x32 MFMA.
// Per-thread staging slice: 16B of A + 16B of B per chunk, 2 chunks/wave.
// Swizzle: LDS slot s of row r holds global 16B-chunk s ^ ((r>>1)&3); readers invert.
__device__ __forceinline__ void gemm_bt_core(
    const short* __restrict__ A, const short* __restrict__ B,
    int ldk, int ksteps, short* lsA, short* lsB, f32x4 acc[4][4])
{
  const int tid  = threadIdx.x;
  const int lane = tid & 63;
  const int wave = tid >> 6;
  const int wr   = (wave >> 1) * 64;
  const int wc   = (wave & 1) * 64;
  const int quad = lane >> 4;
  const int l15  = lane & 15;
  const int sw   = (l15 >> 1) & 3;                       // read-side swizzle
  const int srow = lane >> 2;                            // row within 16-row chunk
  const int cg   = ((lane & 3) ^ ((lane >> 3) & 3)) * 8; // swizzled global chunk (shorts)
  const int c0   = wave * 2;                             // this wave's chunks: c0, c0+1

  const short* pa0 = A + (size_t)(c0 * 16 + srow) * ldk + cg;
  const short* pa1 = A + (size_t)(c0 * 16 + 16 + srow) * ldk + cg;
  const short* pb0 = B + (size_t)(c0 * 16 + srow) * ldk + cg;
  const short* pb1 = B + (size_t)(c0 * 16 + 16 + srow) * ldk + cg;
  short* wA = lsA + c0 * 512 + lane * 8;   // chunk c0 dest; c0+1 at +512
  short* wB = lsB + c0 * 512 + lane * 8;

  // reg set s holds tile k with k&1==s
  bf16x8 ra0[2], ra1[2], rb0[2], rb1[2];

  // prologue: load tiles 0 and 1; stage tile 0 into buf 0
  ra0[0] = *(const bf16x8*)(pa0);
  ra1[0] = *(const bf16x8*)(pa1);
  rb0[0] = *(const bf16x8*)(pb0);
  rb1[0] = *(const bf16x8*)(pb1);
  if (ksteps > 1) {
    ra0[1] = *(const bf16x8*)(pa0 + BK);
    ra1[1] = *(const bf16x8*)(pa1 + BK);
    rb0[1] = *(const bf16x8*)(pb0 + BK);
    rb1[1] = *(const bf16x8*)(pb1 + BK);
  }
  *(bf16x8*)(wA)       = ra0[0];
  *(bf16x8*)(wA + 512) = ra1[0];
  *(bf16x8*)(wB)       = rb0[0];
  *(bf16x8*)(wB + 512) = rb1[0];

  // One step, parity P = ks&1 (compile-time literal at each expansion).
  // barrier -> issue loads k+2 (into set P) -> ds_write k+1 (from set P^1, buf P^1)
  //         -> ds_read buf P -> MFMA
#define GEMM_STEP(ks, P)                                                        \
  {                                                                             \
    __syncthreads();                                                            \
    const int kn = (ks) + 2;                                                    \
    if (kn < ksteps) {                                                          \
      ra0[P] = *(const bf16x8*)(pa0 + (size_t)kn * BK);                         \
      ra1[P] = *(const bf16x8*)(pa1 + (size_t)kn * BK);                         \
      rb0[P] = *(const bf16x8*)(pb0 + (size_t)kn * BK);                         \
      rb1[P] = *(const bf16x8*)(pb1 + (size_t)kn * BK);                         \
    }                                                                           \
    if ((ks) + 1 < ksteps) {                                                    \
      short* dA = wA + ((P) ^ 1) * TILE_SH;                                     \
      short* dB = wB + ((P) ^ 1) * TILE_SH;                                     \
      *(bf16x8*)(dA)       = ra0[(P) ^ 1];                                      \
      *(bf16x8*)(dA + 512) = ra1[(P) ^ 1];                                      \
      *(bf16x8*)(dB)       = rb0[(P) ^ 1];                                      \
      *(bf16x8*)(dB + 512) = rb1[(P) ^ 1];                                      \
    }                                                                           \
    const short* sA = lsA + (P)*TILE_SH;                                        \
    const short* sB = lsB + (P)*TILE_SH;                                        \
    bf16x8 af[4], bf[4];                                                        \
    _Pragma("unroll")                                                           \
    for (int i = 0; i < 4; ++i)                                                 \
      af[i] = *(const bf16x8*)&sA[(wr + i * 16 + l15) * BK + (quad ^ sw) * 8];  \
    _Pragma("unroll")                                                           \
    for (int i = 0; i < 4; ++i)                                                 \
      bf[i] = *(const bf16x8*)&sB[(wc + i * 16 + l15) * BK + (quad ^ sw) * 8];  \
    _Pragma("unroll")                                                           \
    for (int mi = 0; mi < 4; ++mi)                                              \
      _Pragma("unroll")                                                         \
      for (int ni = 0; ni < 4; ++ni)                                            \
        acc[mi][ni] = __builtin_amdgcn_mfma_f32_16x16x32_bf16(                  \
            af[mi], bf[ni], acc[mi][ni], 0, 0, 0);                              \
  }

  // ksteps is always a multiple of 2 at every call site (multiples of 4)
  for (int ks = 0; ks < ksteps; ks += 2) {
    GEMM_STEP(ks, 0);
    GEMM_STEP(ks + 1, 1);
  }
#undef GEMM_STEP
}

// ---------------- converts ----------------

__global__ __launch_bounds__(256) void k_convX(const float* __restrict__ x,
                                               short* __restrict__ y) {
  const size_t i = ((size_t)blockIdx.x * 256 + threadIdx.x) * 4;
  const float4 v = *(const float4*)(x + i);
  s16x4 o;
  o[0] = f2bf(v.x); o[1] = f2bf(v.y); o[2] = f2bf(v.z); o[3] = f2bf(v.w);
  *(s16x4*)(y + i) = o;
}

// transpose 1024x1024 W[i][c] -> bf16 Wt[c][i], 32x32 LDS tiles
__global__ __launch_bounds__(256) void k_convWt(const float* __restrict__ Wq,
                                                const float* __restrict__ Wk,
                                                const float* __restrict__ Wv,
                                                short* __restrict__ Wtq,
                                                short* __restrict__ Wtk,
                                                short* __restrict__ Wtv) {
  const float* W = (blockIdx.z == 0) ? Wq : (blockIdx.z == 1) ? Wk : Wv;
  short* Wt      = (blockIdx.z == 0) ? Wtq : (blockIdx.z == 1) ? Wtk : Wtv;
  __shared__ float t[32][33];
  const int tx = threadIdx.x & 31;
  const int ty = threadIdx.x >> 5;           // 0..7
  const int bc = blockIdx.x * 32;            // c tile
  const int bi = blockIdx.y * 32;            // i tile
#pragma unroll
  for (int j = 0; j < 32; j += 8)
    t[ty + j][tx] = W[(size_t)(bi + ty + j) * 1024 + bc + tx];
  __syncthreads();
#pragma unroll
  for (int j = 0; j < 32; j += 8)
    Wt[(size_t)(bc + ty + j) * 1024 + bi + tx] = f2bf(t[tx][ty + j]);
}

// ---------------- GEMMs ----------------

// Q/K projection: A = Xb [8192 x 1024], B = Wt [1024(c) x 1024(k)], out bf16 [8192 x 1024]
__global__ __launch_bounds__(256) void k_proj_qk(const short* __restrict__ Xb,
                                                 const short* __restrict__ Wtq,
                                                 const short* __restrict__ Wtk,
                                                 short* __restrict__ Qb,
                                                 short* __restrict__ Kb) {
  __shared__ short lsA[2 * TILE_SH];
  __shared__ short lsB[2 * TILE_SH];
  f32x4 acc[4][4];
#pragma unroll
  for (int i = 0; i < 4; ++i)
#pragma unroll
    for (int j = 0; j < 4; ++j) acc[i][j] = 0.f;

  const short* W = blockIdx.z ? Wtk : Wtq;
  short* O       = blockIdx.z ? Kb : Qb;
  const short* A = Xb + (size_t)blockIdx.y * 128 * 1024;
  const short* B = W  + (size_t)blockIdx.x * 128 * 1024;
  gemm_bt_core(A, B, 1024, 32, lsA, lsB, acc);

  const int lane = threadIdx.x & 63, wave = threadIdx.x >> 6;
  const int wr = (wave >> 1) * 64, wc = (wave & 1) * 64;
  const int quad = lane >> 4, l15 = lane & 15;
#pragma unroll
  for (int mi = 0; mi < 4; ++mi)
#pragma unroll
    for (int ni = 0; ni < 4; ++ni)
#pragma unroll
      for (int r = 0; r < 4; ++r) {
        const int rl = wr + mi * 16 + quad * 4 + r;
        const int cl = wc + ni * 16 + l15;
        O[(size_t)(blockIdx.y * 128 + rl) * 1024 + blockIdx.x * 128 + cl] =
            f2bf(acc[mi][ni][r]);
      }
}

// V^T projection: A = Wt_v [1024(i) x 1024(k)], B = Xb_batch [4096(t) x 1024(k)],
// out Vt[b][i][t] bf16
__global__ __launch_bounds__(256) void k_proj_v(const short* __restrict__ Wtv,
                                                const short* __restrict__ Xb,
                                                short* __restrict__ Vt) {
  __shared__ short lsA[2 * TILE_SH];
  __shared__ short lsB[2 * TILE_SH];
  f32x4 acc[4][4];
#pragma unroll
  for (int i = 0; i < 4; ++i)
#pragma unroll
    for (int j = 0; j < 4; ++j) acc[i][j] = 0.f;

  const size_t b = blockIdx.z;
  const short* A = Wtv + (size_t)blockIdx.y * 128 * 1024;
  const short* B = Xb + b * T_SEQ * C_DIM + (size_t)blockIdx.x * 128 * 1024;
  gemm_bt_core(A, B, 1024, 32, lsA, lsB, acc);

  short* O = Vt + b * C_DIM * T_SEQ;
  const int lane = threadIdx.x & 63, wave = threadIdx.x >> 6;
  const int wr = (wave >> 1) * 64, wc = (wave & 1) * 64;
  const int quad = lane >> 4, l15 = lane & 15;
#pragma unroll
  for (int mi = 0; mi < 4; ++mi)
#pragma unroll
    for (int ni = 0; ni < 4; ++ni)
#pragma unroll
      for (int r = 0; r < 4; ++r) {
        const int rl = wr + mi * 16 + quad * 4 + r;   // i local
        const int cl = wc + ni * 16 + l15;            // t local
        O[(size_t)(blockIdx.y * 128 + rl) * T_SEQ + blockIdx.x * 128 + cl] =
            f2bf(acc[mi][ni][r]);
      }
}

// Scores: P[b][n][m] = bf16( (Q_n . K_m) * g^(n-m) * [n>=m] ). Lower-tri tiles only.
__global__ __launch_bounds__(256) void k_scores(const short* __restrict__ Qb,
                                                const short* __restrict__ Kb,
                                                short* __restrict__ P) {
  if (blockIdx.y < blockIdx.x) return;   // pure upper-triangle tile: never read
  __shared__ short lsA[2 * TILE_SH];
  __shared__ short lsB[2 * TILE_SH];
  f32x4 acc[4][4];
#pragma unroll
  for (int i = 0; i < 4; ++i)
#pragma unroll
    for (int j = 0; j < 4; ++j) acc[i][j] = 0.f;

  const size_t b = blockIdx.z;
  const short* A = Qb + b * T_SEQ * C_DIM + (size_t)blockIdx.y * 128 * 1024;
  const short* B = Kb + b * T_SEQ * C_DIM + (size_t)blockIdx.x * 128 * 1024;
  gemm_bt_core(A, B, 1024, 32, lsA, lsB, acc);

  short* Pb = P + b * (size_t)T_SEQ * T_SEQ;
  const int lane = threadIdx.x & 63, wave = threadIdx.x >> 6;
  const int wr = (wave >> 1) * 64, wc = (wave & 1) * 64;
  const int quad = lane >> 4, l15 = lane & 15;
#pragma unroll
  for (int mi = 0; mi < 4; ++mi)
#pragma unroll
    for (int ni = 0; ni < 4; ++ni)
#pragma unroll
      for (int r = 0; r < 4; ++r) {
        const int n = blockIdx.y * 128 + wr + mi * 16 + quad * 4 + r;
        const int m = blockIdx.x * 128 + wc + ni * 16 + l15;
        float v = 0.f;
        if (n >= m) v = acc[mi][ni][r] * exp2f((float)(n - m) * L2G);
        Pb[(size_t)n * T_SEQ + m] = f2bf(v);
      }
}

// PV split-K: out[b][i][t] += sum over one K-chunk of Vt[b][i][m] * P[b][t][m].
// Grid.x = 80 chunks covering t-tiles x=0..31 with ceil((x+1)/8) chunks of <=32
// ksteps each, enumerated BIG-FIRST (x descending). HW fp32 atomics into
// pre-zeroed out.
__global__ __launch_bounds__(256) void k_pv(const short* __restrict__ Vt,
                                            const short* __restrict__ P,
                                            float* __restrict__ out) {
  __shared__ short lsA[2 * TILE_SH];
  __shared__ short lsB[2 * TILE_SH];
  f32x4 acc[4][4];
#pragma unroll
  for (int i = 0; i < 4; ++i)
#pragma unroll
    for (int j = 0; j < 4; ++j) acc[i][j] = 0.f;

  // map blockIdx.x in [0,80) -> (xt, chunk), xt descending
  int cx = blockIdx.x;
  int xt = 0, ch = 0;
  for (int x = 31; x >= 0; --x) {
    const int n = (x + 8) >> 3;          // ceil((x+1)/8)
    if (cx < n) { xt = x; ch = cx; break; }
    cx -= n;
  }
  const int k0 = ch * 32;                            // kstep offset
  const int ks = min((xt + 1) * 4 - k0, 32);         // ksteps this block

  const size_t b = blockIdx.z;
  const short* A = Vt + b * C_DIM * T_SEQ + (size_t)blockIdx.y * 128 * T_SEQ
                      + (size_t)k0 * BK;
  const short* B = P + b * (size_t)T_SEQ * T_SEQ + (size_t)xt * 128 * T_SEQ
                     + (size_t)k0 * BK;
  gemm_bt_core(A, B, T_SEQ, ks, lsA, lsB, acc);

  float* Ob = out + b * (size_t)C_DIM * T_SEQ;
  const int lane = threadIdx.x & 63, wave = threadIdx.x >> 6;
  const int wr = (wave >> 1) * 64, wc = (wave & 1) * 64;
  const int quad = lane >> 4, l15 = lane & 15;
#pragma unroll
  for (int mi = 0; mi < 4; ++mi)
#pragma unroll
    for (int ni = 0; ni < 4; ++ni)
#pragma unroll
      for (int r = 0; r < 4; ++r) {
        const int rl = blockIdx.y * 128 + wr + mi * 16 + quad * 4 + r;  // i
        const int cl = xt * 128 + wc + ni * 16 + l15;                   // t
        unsafeAtomicAdd(&Ob[(size_t)rl * T_SEQ + cl], acc[mi][ni][r]);
      }
}

// ---------------- launch ----------------

extern "C" void kernel_launch(void* const* d_in, const int* in_sizes, int n_in,
                              void* d_out, int out_size, void* d_ws, size_t ws_size,
                              hipStream_t stream) {
  const float* X  = (const float*)d_in[0];
  // d_in[1] att_mask (unused), d_in[2] S_n (zeros, passthrough)
  const float* Wq = (const float*)d_in[3];
  const float* Wk = (const float*)d_in[4];
  const float* Wv = (const float*)d_in[5];
  float* out = (float*)d_out;

  // workspace layout (bytes); total 140,509,184 (~134 MiB)
  char* ws = (char*)d_ws;
  short* Xb  = (short*)(ws);                 // 16,777,216  X bf16 [B*T, I]
  short* Wtq = (short*)(ws + 16777216);      //  2,097,152  Wq^T bf16 [c][i]
  short* Wtk = (short*)(ws + 18874368);      //  2,097,152
  short* Wtv = (short*)(ws + 20971520);      //  2,097,152
  short* Qb  = (short*)(ws + 23068672);      // 16,777,216  [B*T, C]
  short* Kb  = (short*)(ws + 39845888);      // 16,777,216
  short* Vt  = (short*)(ws + 56623104);      // 16,777,216  [B, I, T]
  short* P   = (short*)(ws + 73400320);      // 67,108,864  [B, T, T]

  // zero entire output (PV atomically accumulates; S_n passthrough stays 0)
  hipMemsetAsync(out, 0, (size_t)out_size * sizeof(float), stream);

  k_convX  <<<dim3(8192),       dim3(256), 0, stream>>>(X, Xb);
  k_convWt <<<dim3(32, 32, 3),  dim3(256), 0, stream>>>(Wq, Wk, Wv, Wtq, Wtk, Wtv);
  k_proj_qk<<<dim3(8, 64, 2),   dim3(256), 0, stream>>>(Xb, Wtq, Wtk, Qb, Kb);
  k_proj_v <<<dim3(32, 8, 2),   dim3(256), 0, stream>>>(Wtv, Xb, Vt);
  k_scores <<<dim3(32, 32, 2),  dim3(256), 0, stream>>>(Qb, Kb, P);
  k_pv     <<<dim3(80, 8, 2),   dim3(256), 0, stream>>>(Vt, P, out);
}

// Round 6
// 341.587 us; speedup vs baseline: 1.0441x; 1.0441x over previous
//
#include <hip/hip_runtime.h>
#include <cstdint>
#include <cstddef>

// COINBlock (RetNet-style retention, parallel form) on MI355X.
// Shapes: B=2, T=4096, I=C=1024.
//   Q = X@Wq, K = X@Wk, V = X@Wv            (bf16 MFMA, fp32 accum)
//   P = (Q K^T) * D,  D[n,m] = g^(n-m)*[n>=m]   (lower-tri tiles only)
//   out^T[i][t] = sum_m V^T[i][m] * P[t][m]     (output IS the transposed layout)
// All GEMMs are gemm_bt form: C[m][n] = sum_k A[m][k]*B[n][k], k-contiguous.
// R4: dbuf + single barrier/kstep + XOR swizzle (conflicts 0). R5 (VGPR pipe) reverted.
// R6: staged-bandwidth theory — all GEMMs capped ~390 TF by ~6 TB/s LLC-class
//     staging traffic (16 KB / 1.05 MFLOP). Fix: 256x128 tiles @512 thr
//     (11.4 B/kFLOP) for proj_qk/scores/pv + dispatch order making consecutive
//     blocks share the streamed operand (P-chunk / K-tile) for L2 hits.

using bf16x8 = __attribute__((ext_vector_type(8))) short;
using s16x4  = __attribute__((ext_vector_type(4))) short;
using f32x4  = __attribute__((ext_vector_type(4))) float;

#define BK 32
#define T_SEQ 4096
#define C_DIM 1024
#define ASZ (256 * BK)   // shorts per 256x32 A-tile (16 KB)
#define BSZ (128 * BK)   // shorts per 128x32 B-tile (8 KB)
#define TILE_SH 4096     // shorts per 128x32 tile (8 KB) - 256-thr core

static constexpr float L2G = -0.0144995697f; // log2(0.99)

__device__ __forceinline__ short f2bf(float f) {
  unsigned u = __builtin_bit_cast(unsigned, f);
  u += 0x7FFFu + ((u >> 16) & 1u);   // round-to-nearest-even
  return (short)(u >> 16);
}

// async 16B/lane global->LDS (dest = wave-uniform base + lane*16).
__device__ __forceinline__ void async_ld16(const short* g, const short* l) {
  __builtin_amdgcn_global_load_lds(
      (const __attribute__((address_space(1))) unsigned int*)(uintptr_t)g,
      (__attribute__((address_space(3))) unsigned int*)(unsigned)(uintptr_t)l,
      16, 0, 0);
}

// ---------- 512-thread core: 256x128 tile, 8 waves (4x2), 4x4 MFMA each ----------
// Swizzle: LDS slot s of row r holds global 16B-chunk s ^ ((r>>1)&3).
__device__ __forceinline__ void gemm_bt_core512(
    const short* __restrict__ A, const short* __restrict__ B,
    int ldk, int ksteps, short* lsA, short* lsB, f32x4 acc[4][4])
{
  const int tid  = threadIdx.x;
  const int lane = tid & 63;
  const int wave = tid >> 6;
  const int wr   = (wave >> 1) * 64;   // A-row base (0..192)
  const int wc   = (wave & 1) * 64;    // B-row base (0..64)
  const int quad = lane >> 4;
  const int l15  = lane & 15;
  const int sw   = (l15 >> 1) & 3;
  const int arow = tid >> 2;                              // 0..127
  const int cg   = ((tid & 3) ^ ((tid >> 3) & 3)) * 8;    // swizzled 16B slot (shorts)

  const short* pa0 = A + (size_t)arow * ldk + cg;          // A rows 0..127
  const short* pa1 = A + (size_t)(128 + arow) * ldk + cg;  // A rows 128..255 (same swizzle: 128 row offset keeps (r>>1)&3)
  const short* pb  = B + (size_t)arow * ldk + cg;          // B rows 0..127
  short* wA0 = lsA + tid * 8;
  short* wA1 = lsA + (512 + tid) * 8;
  short* wB  = lsB + tid * 8;

  async_ld16(pa0, wA0);   // prologue: tile 0 -> buf 0
  async_ld16(pa1, wA1);
  async_ld16(pb,  wB);

  for (int ks = 0; ks < ksteps; ++ks) {
    const int buf = ks & 1;
    __syncthreads();   // drains vmcnt -> buf ready; readers of buf^1 done
    if (ks + 1 < ksteps) {
      const size_t ko = (size_t)(ks + 1) * BK;
      const int nb = buf ^ 1;
      async_ld16(pa0 + ko, wA0 + nb * ASZ);
      async_ld16(pa1 + ko, wA1 + nb * ASZ);
      async_ld16(pb  + ko, wB  + nb * BSZ);
    }
    const short* sA = lsA + buf * ASZ;
    const short* sB = lsB + buf * BSZ;
    bf16x8 af[4], bf[4];
#pragma unroll
    for (int i = 0; i < 4; ++i)
      af[i] = *(const bf16x8*)&sA[(wr + i * 16 + l15) * BK + (quad ^ sw) * 8];
#pragma unroll
    for (int i = 0; i < 4; ++i)
      bf[i] = *(const bf16x8*)&sB[(wc + i * 16 + l15) * BK + (quad ^ sw) * 8];
#pragma unroll
    for (int mi = 0; mi < 4; ++mi)
#pragma unroll
      for (int ni = 0; ni < 4; ++ni)
        acc[mi][ni] = __builtin_amdgcn_mfma_f32_16x16x32_bf16(
            af[mi], bf[ni], acc[mi][ni], 0, 0, 0);
  }
}

// ---------- 256-thread core (R4): 128x128 tile, 4 waves (2x2) ----------
__device__ __forceinline__ void stage_tiles256(const short* __restrict__ A,
                                               const short* __restrict__ B,
                                               short* lsA, short* lsB, int buf,
                                               int wave, int lane, int ldk) {
  const int srow = lane >> 2;
  const int cg   = ((lane & 3) ^ ((lane >> 3) & 3)) * 8;
#pragma unroll
  for (int j = 0; j < 2; ++j) {
    const int c   = wave * 2 + j;
    const int row = c * 16 + srow;
    async_ld16(A + (size_t)row * ldk + cg, lsA + buf * TILE_SH + c * 512 + lane * 8);
    async_ld16(B + (size_t)row * ldk + cg, lsB + buf * TILE_SH + c * 512 + lane * 8);
  }
}

__device__ __forceinline__ void gemm_bt_core256(
    const short* __restrict__ A, const short* __restrict__ B,
    int ldk, int ksteps, short* lsA, short* lsB, f32x4 acc[4][4])
{
  const int tid  = threadIdx.x;
  const int lane = tid & 63;
  const int wave = tid >> 6;
  const int wr   = (wave >> 1) * 64;
  const int wc   = (wave & 1) * 64;
  const int quad = lane >> 4;
  const int l15  = lane & 15;
  const int sw   = (l15 >> 1) & 3;

  stage_tiles256(A, B, lsA, lsB, 0, wave, lane, ldk);

  for (int ks = 0; ks < ksteps; ++ks) {
    const int buf = ks & 1;
    __syncthreads();
    if (ks + 1 < ksteps)
      stage_tiles256(A + (size_t)(ks + 1) * BK, B + (size_t)(ks + 1) * BK,
                     lsA, lsB, buf ^ 1, wave, lane, ldk);
    bf16x8 af[4], bf[4];
#pragma unroll
    for (int i = 0; i < 4; ++i)
      af[i] = *(const bf16x8*)&lsA[buf * TILE_SH + (wr + i * 16 + l15) * BK + (quad ^ sw) * 8];
#pragma unroll
    for (int i = 0; i < 4; ++i)
      bf[i] = *(const bf16x8*)&lsB[buf * TILE_SH + (wc + i * 16 + l15) * BK + (quad ^ sw) * 8];
#pragma unroll
    for (int mi = 0; mi < 4; ++mi)
#pragma unroll
      for (int ni = 0; ni < 4; ++ni)
        acc[mi][ni] = __builtin_amdgcn_mfma_f32_16x16x32_bf16(
            af[mi], bf[ni], acc[mi][ni], 0, 0, 0);
  }
}

// ---------------- converts ----------------

__global__ __launch_bounds__(256) void k_convX(const float* __restrict__ x,
                                               short* __restrict__ y) {
  const size_t i = ((size_t)blockIdx.x * 256 + threadIdx.x) * 4;
  const float4 v = *(const float4*)(x + i);
  s16x4 o;
  o[0] = f2bf(v.x); o[1] = f2bf(v.y); o[2] = f2bf(v.z); o[3] = f2bf(v.w);
  *(s16x4*)(y + i) = o;
}

__global__ __launch_bounds__(256) void k_convWt(const float* __restrict__ Wq,
                                                const float* __restrict__ Wk,
                                                const float* __restrict__ Wv,
                                                short* __restrict__ Wtq,
                                                short* __restrict__ Wtk,
                                                short* __restrict__ Wtv) {
  const float* W = (blockIdx.z == 0) ? Wq : (blockIdx.z == 1) ? Wk : Wv;
  short* Wt      = (blockIdx.z == 0) ? Wtq : (blockIdx.z == 1) ? Wtk : Wtv;
  __shared__ float t[32][33];
  const int tx = threadIdx.x & 31;
  const int ty = threadIdx.x >> 5;
  const int bc = blockIdx.x * 32;
  const int bi = blockIdx.y * 32;
#pragma unroll
  for (int j = 0; j < 32; j += 8)
    t[ty + j][tx] = W[(size_t)(bi + ty + j) * 1024 + bc + tx];
  __syncthreads();
#pragma unroll
  for (int j = 0; j < 32; j += 8)
    Wt[(size_t)(bc + ty + j) * 1024 + bi + tx] = f2bf(t[tx][ty + j]);
}

// ---------------- GEMMs ----------------

// Q/K projection: A = Xb m-tile (256 rows), B = Wt n-tile (128 rows). 512 thr.
// grid (8 n-tiles, 32 m-tiles, 2 weights); consecutive x share the A-tile.
__global__ __launch_bounds__(512) void k_proj_qk(const short* __restrict__ Xb,
                                                 const short* __restrict__ Wtq,
                                                 const short* __restrict__ Wtk,
                                                 short* __restrict__ Qb,
                                                 short* __restrict__ Kb) {
  __shared__ short lsA[2 * ASZ];
  __shared__ short lsB[2 * BSZ];
  f32x4 acc[4][4];
#pragma unroll
  for (int i = 0; i < 4; ++i)
#pragma unroll
    for (int j = 0; j < 4; ++j) acc[i][j] = 0.f;

  const short* W = blockIdx.z ? Wtk : Wtq;
  short* O       = blockIdx.z ? Kb : Qb;
  const short* A = Xb + (size_t)blockIdx.y * 256 * 1024;
  const short* B = W  + (size_t)blockIdx.x * 128 * 1024;
  gemm_bt_core512(A, B, 1024, 32, lsA, lsB, acc);

  const int lane = threadIdx.x & 63, wave = threadIdx.x >> 6;
  const int wr = (wave >> 1) * 64, wc = (wave & 1) * 64;
  const int quad = lane >> 4, l15 = lane & 15;
#pragma unroll
  for (int mi = 0; mi < 4; ++mi)
#pragma unroll
    for (int ni = 0; ni < 4; ++ni)
#pragma unroll
      for (int r = 0; r < 4; ++r) {
        const int rl = wr + mi * 16 + quad * 4 + r;
        const int cl = wc + ni * 16 + l15;
        O[(size_t)(blockIdx.y * 256 + rl) * 1024 + blockIdx.x * 128 + cl] =
            f2bf(acc[mi][ni][r]);
      }
}

// V^T projection: A = Wt_v i-tile (128), B = Xb t-tile (128). 256 thr (R4).
__global__ __launch_bounds__(256) void k_proj_v(const short* __restrict__ Wtv,
                                                const short* __restrict__ Xb,
                                                short* __restrict__ Vt) {
  __shared__ short lsA[2 * TILE_SH];
  __shared__ short lsB[2 * TILE_SH];
  f32x4 acc[4][4];
#pragma unroll
  for (int i = 0; i < 4; ++i)
#pragma unroll
    for (int j = 0; j < 4; ++j) acc[i][j] = 0.f;

  const size_t b = blockIdx.z;
  const short* A = Wtv + (size_t)blockIdx.y * 128 * 1024;
  const short* B = Xb + b * T_SEQ * C_DIM + (size_t)blockIdx.x * 128 * 1024;
  gemm_bt_core256(A, B, 1024, 32, lsA, lsB, acc);

  short* O = Vt + b * C_DIM * T_SEQ;
  const int lane = threadIdx.x & 63, wave = threadIdx.x >> 6;
  const int wr = (wave >> 1) * 64, wc = (wave & 1) * 64;
  const int quad = lane >> 4, l15 = lane & 15;
#pragma unroll
  for (int mi = 0; mi < 4; ++mi)
#pragma unroll
    for (int ni = 0; ni < 4; ++ni)
#pragma unroll
      for (int r = 0; r < 4; ++r) {
        const int rl = wr + mi * 16 + quad * 4 + r;
        const int cl = wc + ni * 16 + l15;
        O[(size_t)(blockIdx.y * 128 + rl) * T_SEQ + blockIdx.x * 128 + cl] =
            f2bf(acc[mi][ni][r]);
      }
}

// Scores: A = Q n-tile (256 rows), B = K m-tile (128 rows). 512 thr.
// grid (16 n-tiles, 32 m-tiles, 2); consecutive x share B = K[y] (L2-hot).
// Skip tiles entirely above the diagonal: all n < m  <=>  y >= 2x+2.
__global__ __launch_bounds__(512) void k_scores(const short* __restrict__ Qb,
                                                const short* __restrict__ Kb,
                                                short* __restrict__ P) {
  if (blockIdx.y >= 2 * blockIdx.x + 2) return;
  __shared__ short lsA[2 * ASZ];
  __shared__ short lsB[2 * BSZ];
  f32x4 acc[4][4];
#pragma unroll
  for (int i = 0; i < 4; ++i)
#pragma unroll
    for (int j = 0; j < 4; ++j) acc[i][j] = 0.f;

  const size_t b = blockIdx.z;
  const short* A = Qb + b * T_SEQ * C_DIM + (size_t)blockIdx.x * 256 * 1024;
  const short* B = Kb + b * T_SEQ * C_DIM + (size_t)blockIdx.y * 128 * 1024;
  gemm_bt_core512(A, B, 1024, 32, lsA, lsB, acc);

  short* Pb = P + b * (size_t)T_SEQ * T_SEQ;
  const int lane = threadIdx.x & 63, wave = threadIdx.x >> 6;
  const int wr = (wave >> 1) * 64, wc = (wave & 1) * 64;
  const int quad = lane >> 4, l15 = lane & 15;
#pragma unroll
  for (int mi = 0; mi < 4; ++mi)
#pragma unroll
    for (int ni = 0; ni < 4; ++ni)
#pragma unroll
      for (int r = 0; r < 4; ++r) {
        const int n = blockIdx.x * 256 + wr + mi * 16 + quad * 4 + r;
        const int m = blockIdx.y * 128 + wc + ni * 16 + l15;
        float v = 0.f;
        if (n >= m) v = acc[mi][ni][r] * exp2f((float)(n - m) * L2G);
        Pb[(size_t)n * T_SEQ + m] = f2bf(v);
      }
}

// PV split-K: A = Vt i-tile (256 rows), B = P t-tile (128 rows), K-chunk <=32.
// grid (4 i-tiles FASTEST -> the 4 sharers of each P-chunk are dispatch-adjacent,
// 80 chunk-combos big-first, 2). HW fp32 atomics into pre-zeroed out.
__global__ __launch_bounds__(512) void k_pv(const short* __restrict__ Vt,
                                            const short* __restrict__ P,
                                            float* __restrict__ out) {
  __shared__ short lsA[2 * ASZ];
  __shared__ short lsB[2 * BSZ];
  f32x4 acc[4][4];
#pragma unroll
  for (int i = 0; i < 4; ++i)
#pragma unroll
    for (int j = 0; j < 4; ++j) acc[i][j] = 0.f;

  // map blockIdx.y in [0,80) -> (xt, chunk), xt descending (big-first)
  int cx = blockIdx.y;
  int xt = 0, ch = 0;
  for (int x = 31; x >= 0; --x) {
    const int n = (x + 8) >> 3;          // ceil((x+1)/8)
    if (cx < n) { xt = x; ch = cx; break; }
    cx -= n;
  }
  const int k0 = ch * 32;
  const int ks = min((xt + 1) * 4 - k0, 32);

  const size_t b = blockIdx.z;
  const short* A = Vt + b * C_DIM * T_SEQ + (size_t)blockIdx.x * 256 * T_SEQ
                      + (size_t)k0 * BK;
  const short* B = P + b * (size_t)T_SEQ * T_SEQ + (size_t)xt * 128 * T_SEQ
                     + (size_t)k0 * BK;
  gemm_bt_core512(A, B, T_SEQ, ks, lsA, lsB, acc);

  float* Ob = out + b * (size_t)C_DIM * T_SEQ;
  const int lane = threadIdx.x & 63, wave = threadIdx.x >> 6;
  const int wr = (wave >> 1) * 64, wc = (wave & 1) * 64;
  const int quad = lane >> 4, l15 = lane & 15;
#pragma unroll
  for (int mi = 0; mi < 4; ++mi)
#pragma unroll
    for (int ni = 0; ni < 4; ++ni)
#pragma unroll
      for (int r = 0; r < 4; ++r) {
        const int rl = blockIdx.x * 256 + wr + mi * 16 + quad * 4 + r;  // i
        const int cl = xt * 128 + wc + ni * 16 + l15;                   // t
        unsafeAtomicAdd(&Ob[(size_t)rl * T_SEQ + cl], acc[mi][ni][r]);
      }
}

// ---------------- launch ----------------

extern "C" void kernel_launch(void* const* d_in, const int* in_sizes, int n_in,
                              void* d_out, int out_size, void* d_ws, size_t ws_size,
                              hipStream_t stream) {
  const float* X  = (const float*)d_in[0];
  // d_in[1] att_mask (unused), d_in[2] S_n (zeros, passthrough)
  const float* Wq = (const float*)d_in[3];
  const float* Wk = (const float*)d_in[4];
  const float* Wv = (const float*)d_in[5];
  float* out = (float*)d_out;

  char* ws = (char*)d_ws;
  short* Xb  = (short*)(ws);                 // 16,777,216  X bf16 [B*T, I]
  short* Wtq = (short*)(ws + 16777216);      //  2,097,152  Wq^T bf16 [c][i]
  short* Wtk = (short*)(ws + 18874368);      //  2,097,152
  short* Wtv = (short*)(ws + 20971520);      //  2,097,152
  short* Qb  = (short*)(ws + 23068672);      // 16,777,216  [B*T, C]
  short* Kb  = (short*)(ws + 39845888);      // 16,777,216
  short* Vt  = (short*)(ws + 56623104);      // 16,777,216  [B, I, T]
  short* P   = (short*)(ws + 73400320);      // 67,108,864  [B, T, T]

  // zero entire output (PV atomically accumulates; S_n passthrough stays 0)
  hipMemsetAsync(out, 0, (size_t)out_size * sizeof(float), stream);

  k_convX  <<<dim3(8192),       dim3(256), 0, stream>>>(X, Xb);
  k_convWt <<<dim3(32, 32, 3),  dim3(256), 0, stream>>>(Wq, Wk, Wv, Wtq, Wtk, Wtv);
  k_proj_qk<<<dim3(8, 32, 2),   dim3(512), 0, stream>>>(Xb, Wtq, Wtk, Qb, Kb);
  k_proj_v <<<dim3(32, 8, 2),   dim3(256), 0, stream>>>(Wtv, Xb, Vt);
  k_scores <<<dim3(16, 32, 2),  dim3(512), 0, stream>>>(Qb, Kb, P);
  k_pv     <<<dim3(4, 80, 2),   dim3(512), 0, stream>>>(Vt, P, out);
}

// Round 8
// 340.555 us; speedup vs baseline: 1.0473x; 1.0030x over previous
//
#include <hip/hip_runtime.h>
#include <cstdint>
#include <cstddef>

// COINBlock (RetNet-style retention, parallel form) on MI355X.
// Shapes: B=2, T=4096, I=C=1024.
//   Q = X@Wq, K = X@Wk, V = X@Wv            (bf16 MFMA, fp32 accum)
//   P = (Q K^T) * D,  D[n,m] = g^(n-m)*[n>=m]   (lower-tri tiles only)
//   out^T[i][t] = sum_m V^T[i][m] * P[t][m]     (output IS the transposed layout)
// All GEMMs are gemm_bt form: C[m][n] = sum_k A[m][k]*B[n][k], k-contiguous.
// R4: dbuf + 1 barrier/kstep + XOR swizzle (conflicts 0) -> all GEMMs ~390 TF.
// R6: bigger tiles NEUTRAL -> staged-BW theory falsified. Invariant R2-R6:
//     MfmaUtil ~13% -- every barrier's vmcnt(0) drains loads at most one
//     kstep old (latency-coupled, not BW-bound).
// R7: quad-buffered LDS, ONE barrier per TWO ksteps -- FAILED on an indexing
//     bug (absolute kstep offsets applied to an advancing pointer).
// R8: R7 with fixed staging (base pointers never mutate; all offsets absolute).
//     barrier -> prefetch p+2,p+3 (bufs 2,3) -> compute p,p+1 (bufs 0,1)
//     barrier -> prefetch p+4,p+5 (bufs 0,1) -> compute p+2,p+3 (bufs 2,3)

using bf16x8 = __attribute__((ext_vector_type(8))) short;
using s16x4  = __attribute__((ext_vector_type(4))) short;
using f32x4  = __attribute__((ext_vector_type(4))) float;

#define BK 32
#define TILE_SH 4096   // shorts per 128x32 tile (8 KB)
#define T_SEQ 4096
#define C_DIM 1024

static constexpr float L2G = -0.0144995697f; // log2(0.99)

__device__ __forceinline__ short f2bf(float f) {
  unsigned u = __builtin_bit_cast(unsigned, f);
  u += 0x7FFFu + ((u >> 16) & 1u);   // round-to-nearest-even
  return (short)(u >> 16);
}

// async 16B/lane global->LDS (dest = wave-uniform base + lane*16).
__device__ __forceinline__ void async_ld16(const short* g, const short* l) {
  __builtin_amdgcn_global_load_lds(
      (const __attribute__((address_space(1))) unsigned int*)(uintptr_t)g,
      (__attribute__((address_space(3))) unsigned int*)(unsigned)(uintptr_t)l,
      16, 0, 0);
}

// Stage one 128x32 A-tile + B-tile (kstep `k`) into LDS buffer `buf` (0..3).
// Swizzle: LDS slot s of row r holds global 16B-chunk s ^ ((r>>1)&3); readers invert.
__device__ __forceinline__ void stage_tiles(const short* __restrict__ A,
                                            const short* __restrict__ B,
                                            int k, short* lsA, short* lsB, int buf,
                                            int wave, int lane, int ldk) {
  const int srow = lane >> 2;
  const int cg   = ((lane & 3) ^ ((lane >> 3) & 3)) * 8;
  const size_t ko = (size_t)k * BK;
#pragma unroll
  for (int j = 0; j < 2; ++j) {
    const int c   = wave * 2 + j;        // 8 chunks of 16 rows per tile
    const int row = c * 16 + srow;
    async_ld16(A + (size_t)row * ldk + ko + cg, lsA + buf * TILE_SH + c * 512 + lane * 8);
    async_ld16(B + (size_t)row * ldk + ko + cg, lsB + buf * TILE_SH + c * 512 + lane * 8);
  }
}

// K-loop core: 128x128 tile, 4 waves (2x2), 4x4 of 16x16x32 MFMA per wave.
// Quad-buffered: one barrier per 2 ksteps. ksteps MUST be a multiple of 4.
// Base pointers A,B are NEVER advanced; all kstep offsets absolute (R7 bugfix).
__device__ __forceinline__ void gemm_bt_core(
    const short* __restrict__ A, const short* __restrict__ B,
    int ldk, int ksteps, short* lsA, short* lsB, f32x4 acc[4][4])
{
  const int tid  = threadIdx.x;
  const int lane = tid & 63;
  const int wave = tid >> 6;
  const int wr   = (wave >> 1) * 64;
  const int wc   = (wave & 1) * 64;
  const int quad = lane >> 4;
  const int l15  = lane & 15;
  const int sw   = (l15 >> 1) & 3;

#define COMPUTE_STEP(BUF)                                                           \
  {                                                                                 \
    const short* sA = lsA + (BUF)*TILE_SH;                                          \
    const short* sB = lsB + (BUF)*TILE_SH;                                          \
    bf16x8 af[4], bf[4];                                                            \
    _Pragma("unroll")                                                               \
    for (int i = 0; i < 4; ++i)                                                     \
      af[i] = *(const bf16x8*)&sA[(wr + i * 16 + l15) * BK + (quad ^ sw) * 8];      \
    _Pragma("unroll")                                                               \
    for (int i = 0; i < 4; ++i)                                                     \
      bf[i] = *(const bf16x8*)&sB[(wc + i * 16 + l15) * BK + (quad ^ sw) * 8];      \
    _Pragma("unroll")                                                               \
    for (int mi = 0; mi < 4; ++mi)                                                  \
      _Pragma("unroll")                                                             \
      for (int ni = 0; ni < 4; ++ni)                                                \
        acc[mi][ni] = __builtin_amdgcn_mfma_f32_16x16x32_bf16(                      \
            af[mi], bf[ni], acc[mi][ni], 0, 0, 0);                                  \
  }

  // prologue: tiles 0,1 -> bufs 0,1
  stage_tiles(A, B, 0, lsA, lsB, 0, wave, lane, ldk);
  stage_tiles(A, B, 1, lsA, lsB, 1, wave, lane, ldk);

  for (int p = 0; p < ksteps; p += 4) {
    // pair A: barrier drains bufs 0,1 loads; prefetch p+2,p+3 -> bufs 2,3;
    // compute tiles p,p+1 from bufs 0,1
    __syncthreads();
    if (p + 2 < ksteps) stage_tiles(A, B, p + 2, lsA, lsB, 2, wave, lane, ldk);
    if (p + 3 < ksteps) stage_tiles(A, B, p + 3, lsA, lsB, 3, wave, lane, ldk);
    COMPUTE_STEP(0);
    COMPUTE_STEP(1);

    // pair B: barrier drains bufs 2,3 loads; prefetch p+4,p+5 -> bufs 0,1;
    // compute tiles p+2,p+3 from bufs 2,3
    __syncthreads();
    if (p + 4 < ksteps) stage_tiles(A, B, p + 4, lsA, lsB, 0, wave, lane, ldk);
    if (p + 5 < ksteps) stage_tiles(A, B, p + 5, lsA, lsB, 1, wave, lane, ldk);
    COMPUTE_STEP(2);
    COMPUTE_STEP(3);
  }
#undef COMPUTE_STEP
}

// ---------------- converts ----------------

__global__ __launch_bounds__(256) void k_convX(const float* __restrict__ x,
                                               short* __restrict__ y) {
  const size_t i = ((size_t)blockIdx.x * 256 + threadIdx.x) * 4;
  const float4 v = *(const float4*)(x + i);
  s16x4 o;
  o[0] = f2bf(v.x); o[1] = f2bf(v.y); o[2] = f2bf(v.z); o[3] = f2bf(v.w);
  *(s16x4*)(y + i) = o;
}

// transpose 1024x1024 W[i][c] -> bf16 Wt[c][i], 32x32 LDS tiles
__global__ __launch_bounds__(256) void k_convWt(const float* __restrict__ Wq,
                                                const float* __restrict__ Wk,
                                                const float* __restrict__ Wv,
                                                short* __restrict__ Wtq,
                                                short* __restrict__ Wtk,
                                                short* __restrict__ Wtv) {
  const float* W = (blockIdx.z == 0) ? Wq : (blockIdx.z == 1) ? Wk : Wv;
  short* Wt      = (blockIdx.z == 0) ? Wtq : (blockIdx.z == 1) ? Wtk : Wtv;
  __shared__ float t[32][33];
  const int tx = threadIdx.x & 31;
  const int ty = threadIdx.x >> 5;
  const int bc = blockIdx.x * 32;
  const int bi = blockIdx.y * 32;
#pragma unroll
  for (int j = 0; j < 32; j += 8)
    t[ty + j][tx] = W[(size_t)(bi + ty + j) * 1024 + bc + tx];
  __syncthreads();
#pragma unroll
  for (int j = 0; j < 32; j += 8)
    Wt[(size_t)(bc + ty + j) * 1024 + bi + tx] = f2bf(t[tx][ty + j]);
}

// ---------------- GEMMs ----------------

// Q/K projection: A = Xb [8192 x 1024], B = Wt [1024(c) x 1024(k)].
__global__ __launch_bounds__(256) void k_proj_qk(const short* __restrict__ Xb,
                                                 const short* __restrict__ Wtq,
                                                 const short* __restrict__ Wtk,
                                                 short* __restrict__ Qb,
                                                 short* __restrict__ Kb) {
  __shared__ short lsA[4 * TILE_SH];
  __shared__ short lsB[4 * TILE_SH];
  f32x4 acc[4][4];
#pragma unroll
  for (int i = 0; i < 4; ++i)
#pragma unroll
    for (int j = 0; j < 4; ++j) acc[i][j] = 0.f;

  const short* W = blockIdx.z ? Wtk : Wtq;
  short* O       = blockIdx.z ? Kb : Qb;
  const short* A = Xb + (size_t)blockIdx.y * 128 * 1024;
  const short* B = W  + (size_t)blockIdx.x * 128 * 1024;
  gemm_bt_core(A, B, 1024, 32, lsA, lsB, acc);

  const int lane = threadIdx.x & 63, wave = threadIdx.x >> 6;
  const int wr = (wave >> 1) * 64, wc = (wave & 1) * 64;
  const int quad = lane >> 4, l15 = lane & 15;
#pragma unroll
  for (int mi = 0; mi < 4; ++mi)
#pragma unroll
    for (int ni = 0; ni < 4; ++ni)
#pragma unroll
      for (int r = 0; r < 4; ++r) {
        const int rl = wr + mi * 16 + quad * 4 + r;
        const int cl = wc + ni * 16 + l15;
        O[(size_t)(blockIdx.y * 128 + rl) * 1024 + blockIdx.x * 128 + cl] =
            f2bf(acc[mi][ni][r]);
      }
}

// V^T projection: A = Wt_v [1024(i) x 1024(k)], B = Xb batch t-tile.
__global__ __launch_bounds__(256) void k_proj_v(const short* __restrict__ Wtv,
                                                const short* __restrict__ Xb,
                                                short* __restrict__ Vt) {
  __shared__ short lsA[4 * TILE_SH];
  __shared__ short lsB[4 * TILE_SH];
  f32x4 acc[4][4];
#pragma unroll
  for (int i = 0; i < 4; ++i)
#pragma unroll
    for (int j = 0; j < 4; ++j) acc[i][j] = 0.f;

  const size_t b = blockIdx.z;
  const short* A = Wtv + (size_t)blockIdx.y * 128 * 1024;
  const short* B = Xb + b * T_SEQ * C_DIM + (size_t)blockIdx.x * 128 * 1024;
  gemm_bt_core(A, B, 1024, 32, lsA, lsB, acc);

  short* O = Vt + b * C_DIM * T_SEQ;
  const int lane = threadIdx.x & 63, wave = threadIdx.x >> 6;
  const int wr = (wave >> 1) * 64, wc = (wave & 1) * 64;
  const int quad = lane >> 4, l15 = lane & 15;
#pragma unroll
  for (int mi = 0; mi < 4; ++mi)
#pragma unroll
    for (int ni = 0; ni < 4; ++ni)
#pragma unroll
      for (int r = 0; r < 4; ++r) {
        const int rl = wr + mi * 16 + quad * 4 + r;
        const int cl = wc + ni * 16 + l15;
        O[(size_t)(blockIdx.y * 128 + rl) * T_SEQ + blockIdx.x * 128 + cl] =
            f2bf(acc[mi][ni][r]);
      }
}

// Scores: A = Q n-tile (y), B = K m-tile (x); skip pure-upper tiles (y < x).
__global__ __launch_bounds__(256) void k_scores(const short* __restrict__ Qb,
                                                const short* __restrict__ Kb,
                                                short* __restrict__ P) {
  if (blockIdx.y < blockIdx.x) return;
  __shared__ short lsA[4 * TILE_SH];
  __shared__ short lsB[4 * TILE_SH];
  f32x4 acc[4][4];
#pragma unroll
  for (int i = 0; i < 4; ++i)
#pragma unroll
    for (int j = 0; j < 4; ++j) acc[i][j] = 0.f;

  const size_t b = blockIdx.z;
  const short* A = Qb + b * T_SEQ * C_DIM + (size_t)blockIdx.y * 128 * 1024;
  const short* B = Kb + b * T_SEQ * C_DIM + (size_t)blockIdx.x * 128 * 1024;
  gemm_bt_core(A, B, 1024, 32, lsA, lsB, acc);

  short* Pb = P + b * (size_t)T_SEQ * T_SEQ;
  const int lane = threadIdx.x & 63, wave = threadIdx.x >> 6;
  const int wr = (wave >> 1) * 64, wc = (wave & 1) * 64;
  const int quad = lane >> 4, l15 = lane & 15;
#pragma unroll
  for (int mi = 0; mi < 4; ++mi)
#pragma unroll
    for (int ni = 0; ni < 4; ++ni)
#pragma unroll
      for (int r = 0; r < 4; ++r) {
        const int n = blockIdx.y * 128 + wr + mi * 16 + quad * 4 + r;
        const int m = blockIdx.x * 128 + wc + ni * 16 + l15;
        float v = 0.f;
        if (n >= m) v = acc[mi][ni][r] * exp2f((float)(n - m) * L2G);
        Pb[(size_t)n * T_SEQ + m] = f2bf(v);
      }
}

// PV split-K: out[b][i][t] += K-chunk of Vt[b][i][:] . P[b][t][:].
// grid (8 i-tiles fastest, 80 chunk-combos big-first, 2 batches).
// HW fp32 atomics into pre-zeroed out.
__global__ __launch_bounds__(256) void k_pv(const short* __restrict__ Vt,
                                            const short* __restrict__ P,
                                            float* __restrict__ out) {
  __shared__ short lsA[4 * TILE_SH];
  __shared__ short lsB[4 * TILE_SH];
  f32x4 acc[4][4];
#pragma unroll
  for (int i = 0; i < 4; ++i)
#pragma unroll
    for (int j = 0; j < 4; ++j) acc[i][j] = 0.f;

  // map blockIdx.y in [0,80) -> (xt, chunk), xt descending (big-first)
  int cx = blockIdx.y;
  int xt = 0, ch = 0;
  for (int x = 31; x >= 0; --x) {
    const int n = (x + 8) >> 3;          // ceil((x+1)/8)
    if (cx < n) { xt = x; ch = cx; break; }
    cx -= n;
  }
  const int k0 = ch * 32;                        // kstep offset
  const int ks = min((xt + 1) * 4 - k0, 32);     // ksteps (multiple of 4, >=4)

  const size_t b = blockIdx.z;
  const short* A = Vt + b * C_DIM * T_SEQ + (size_t)blockIdx.x * 128 * T_SEQ
                      + (size_t)k0 * BK;
  const short* B = P + b * (size_t)T_SEQ * T_SEQ + (size_t)xt * 128 * T_SEQ
                     + (size_t)k0 * BK;
  gemm_bt_core(A, B, T_SEQ, ks, lsA, lsB, acc);

  float* Ob = out + b * (size_t)C_DIM * T_SEQ;
  const int lane = threadIdx.x & 63, wave = threadIdx.x >> 6;
  const int wr = (wave >> 1) * 64, wc = (wave & 1) * 64;
  const int quad = lane >> 4, l15 = lane & 15;
#pragma unroll
  for (int mi = 0; mi < 4; ++mi)
#pragma unroll
    for (int ni = 0; ni < 4; ++ni)
#pragma unroll
      for (int r = 0; r < 4; ++r) {
        const int rl = blockIdx.x * 128 + wr + mi * 16 + quad * 4 + r;  // i
        const int cl = xt * 128 + wc + ni * 16 + l15;                   // t
        unsafeAtomicAdd(&Ob[(size_t)rl * T_SEQ + cl], acc[mi][ni][r]);
      }
}

// ---------------- launch ----------------

extern "C" void kernel_launch(void* const* d_in, const int* in_sizes, int n_in,
                              void* d_out, int out_size, void* d_ws, size_t ws_size,
                              hipStream_t stream) {
  const float* X  = (const float*)d_in[0];
  // d_in[1] att_mask (unused), d_in[2] S_n (zeros, passthrough)
  const float* Wq = (const float*)d_in[3];
  const float* Wk = (const float*)d_in[4];
  const float* Wv = (const float*)d_in[5];
  float* out = (float*)d_out;

  char* ws = (char*)d_ws;
  short* Xb  = (short*)(ws);                 // 16,777,216  X bf16 [B*T, I]
  short* Wtq = (short*)(ws + 16777216);      //  2,097,152  Wq^T bf16 [c][i]
  short* Wtk = (short*)(ws + 18874368);      //  2,097,152
  short* Wtv = (short*)(ws + 20971520);      //  2,097,152
  short* Qb  = (short*)(ws + 23068672);      // 16,777,216  [B*T, C]
  short* Kb  = (short*)(ws + 39845888);      // 16,777,216
  short* Vt  = (short*)(ws + 56623104);      // 16,777,216  [B, I, T]
  short* P   = (short*)(ws + 73400320);      // 67,108,864  [B, T, T]

  // zero entire output (PV atomically accumulates; S_n passthrough stays 0)
  hipMemsetAsync(out, 0, (size_t)out_size * sizeof(float), stream);

  k_convX  <<<dim3(8192),       dim3(256), 0, stream>>>(X, Xb);
  k_convWt <<<dim3(32, 32, 3),  dim3(256), 0, stream>>>(Wq, Wk, Wv, Wtq, Wtk, Wtv);
  k_proj_qk<<<dim3(8, 64, 2),   dim3(256), 0, stream>>>(Xb, Wtq, Wtk, Qb, Kb);
  k_proj_v <<<dim3(32, 8, 2),   dim3(256), 0, stream>>>(Wtv, Xb, Vt);
  k_scores <<<dim3(32, 32, 2),  dim3(256), 0, stream>>>(Qb, Kb, P);
  k_pv     <<<dim3(8, 80, 2),   dim3(256), 0, stream>>>(Vt, P, out);
}